// Round 4
// baseline (113.702 us; speedup 1.0000x reference)
//
#include <hip/hip_runtime.h>
#include <math.h>

// ---------------------------------------------------------------------------
// AUV Fossen 6-DOF RK2 step, K independent 13-float states. Single fused
// kernel, 512 elements/block (2 per thread, processed sequentially) so the
// per-thread uniform 6x6 Gauss-Jordan inverse + barrier pairs amortize 2x.
// Memory floor: 128 B/elem -> ~67 MB, ~11 us at achievable HBM BW.
// Measured context: dur_us includes ~95 us of harness reset (256 MiB d_ws
// poison + restores) outside kernel control.
// ---------------------------------------------------------------------------

#define ELEMS 512   // elements per block (2 per 256-thread block thread)

__device__ __forceinline__ void fossen_dot(const float* __restrict__ X,
                                           const float* __restrict__ U,
                                           const float* __restrict__ Mi,   // regs
                                           const float* __restrict__ mTot, // s_load
                                           const float* __restrict__ linDamp,
                                           const float* __restrict__ linDampFow,
                                           const float* __restrict__ qdiag, // regs[6]
                                           const float* __restrict__ cgcb,  // regs[6]
                                           float fgz, float fbz,
                                           float* __restrict__ xd)
{
    const float qx = X[3], qy = X[4], qz = X[5], qw = X[6];
    const float r00 = 1.f - 2.f*(qy*qy + qz*qz);
    const float r01 = 2.f*(qx*qy - qz*qw);
    const float r02 = 2.f*(qx*qz + qy*qw);
    const float r10 = 2.f*(qx*qy + qz*qw);
    const float r11 = 1.f - 2.f*(qx*qx + qz*qz);
    const float r12 = 2.f*(qy*qz - qx*qw);
    const float r20 = 2.f*(qx*qz - qy*qw);
    const float r21 = 2.f*(qy*qz + qx*qw);
    const float r22 = 1.f - 2.f*(qx*qx + qy*qy);

    const float v0 = X[7],  v1 = X[8],  v2 = X[9];
    const float v3 = X[10], v4 = X[11], v5 = X[12];

    xd[0] = r00*v0 + r01*v1 + r02*v2;
    xd[1] = r10*v0 + r11*v1 + r12*v2;
    xd[2] = r20*v0 + r21*v1 + r22*v2;
    xd[3] = 0.5f*(-qx*v3 - qy*v4 - qz*v5);
    xd[4] = 0.5f*( qw*v3 - qz*v4 + qy*v5);
    xd[5] = 0.5f*( qz*v3 + qw*v4 - qx*v5);
    xd[6] = 0.5f*(-qy*v3 + qx*v4 + qw*v5);

    const float v[6] = {v0, v1, v2, v3, v4, v5};

    // P = -Dv : P_i = (LD v)_i + v_i (LDF v)_i + QD_i |v_i| v_i
    float P[6];
#pragma unroll
    for (int i = 0; i < 6; ++i) {
        float ld = 0.f, ldf = 0.f;
#pragma unroll
        for (int j = 0; j < 6; ++j) {
            ld  += linDamp[i*6 + j]    * v[j];
            ldf += linDampFow[i*6 + j] * v[j];
        }
        P[i] = ld + v[i]*ldf + qdiag[i] * fabsf(v[i]) * v[i];
    }

    // Coriolis via mv = M v, then cross products (skew(a)b = a x b)
    float mv[6];
#pragma unroll
    for (int i = 0; i < 6; ++i) {
        float s = 0.f;
#pragma unroll
        for (int j = 0; j < 6; ++j) s += mTot[i*6 + j] * v[j];
        mv[i] = s;
    }
    float Cv[6];
    Cv[0] = -(mv[1]*v5 - mv[2]*v4);
    Cv[1] = -(mv[2]*v3 - mv[0]*v5);
    Cv[2] = -(mv[0]*v4 - mv[1]*v3);
    Cv[3] = -(mv[1]*v2 - mv[2]*v1) - (mv[4]*v5 - mv[5]*v4);
    Cv[4] = -(mv[2]*v0 - mv[0]*v2) - (mv[5]*v3 - mv[3]*v5);
    Cv[5] = -(mv[0]*v1 - mv[1]*v0) - (mv[3]*v4 - mv[4]*v3);

    // restoring (only row 2 of rot enters)
    const float fb0 = r20*fgz, fb1 = r21*fgz, fb2 = r22*fgz;
    const float bb0 = r20*fbz, bb1 = r21*fbz, bb2 = r22*fbz;
    const float cgx = cgcb[0], cgy = cgcb[1], cgz = cgcb[2];
    const float cbx = cgcb[3], cby = cgcb[4], cbz = cgcb[5];
    const float m0 = cgy*fb2 - cgz*fb1 + cby*bb2 - cbz*bb1;
    const float m1 = cgz*fb0 - cgx*fb2 + cbz*bb0 - cbx*bb2;
    const float m2 = cgx*fb1 - cgy*fb0 + cbx*bb1 - cby*bb0;
    const float g[6] = { -(fb0+bb0), -(fb1+bb1), -(fb2+bb2), -m0, -m1, -m2 };

    float rhs[6];
#pragma unroll
    for (int i = 0; i < 6; ++i) rhs[i] = U[i] - Cv[i] + P[i] - g[i];

    // vDot = Minv @ rhs   (Minv in VGPRs, computed once per thread)
#pragma unroll
    for (int i = 0; i < 6; ++i) {
        float s = 0.f;
#pragma unroll
        for (int j = 0; j < 6; ++j) s += Mi[i*6 + j] * rhs[j];
        xd[7+i] = s;
    }
}

__global__ void __launch_bounds__(256)
auv_rk2_fused(const float* __restrict__ x, const float* __restrict__ u,
              const float* __restrict__ mass, const float* __restrict__ volume,
              const float* __restrict__ cog, const float* __restrict__ cob,
              const float* __restrict__ mTot, const float* __restrict__ linDamp,
              const float* __restrict__ linDampFow,
              const float* __restrict__ quadDamp,
              float* __restrict__ out, int K)
{
    __shared__ float sx[ELEMS * 13];   // 26624 B, packed rows of 13 floats
    const int tid   = threadIdx.x;
    const int base  = blockIdx.x * ELEMS;
    const int nElem = min(ELEMS, K - base);

    // ---- async global->LDS staging (512*13 floats = 1664 float4) ----
    if (nElem == ELEMS) {
        const float* gx = x + (size_t)base * 13;
#pragma unroll
        for (int it = 0; it < 6; ++it) {
            const int k = it*256 + tid;       // float4 index
            __builtin_amdgcn_global_load_lds(
                (const __attribute__((address_space(1))) void*)(gx + (size_t)k*4),
                (__attribute__((address_space(3))) void*)(&sx[k*4]), 16, 0, 0);
        }
        if (tid < 128) {                       // waves 0,1 (wave-aligned branch)
            const int k = 1536 + tid;
            __builtin_amdgcn_global_load_lds(
                (const __attribute__((address_space(1))) void*)(gx + (size_t)k*4),
                (__attribute__((address_space(3))) void*)(&sx[k*4]), 16, 0, 0);
        }
    } else {
        for (int k = tid; k < nElem*13; k += 256) sx[k] = x[(size_t)base*13 + k];
    }

    // ---- per-thread (uniform) constants; overlaps the in-flight staging ----
    float qdiag[6], cgcb[6];
#pragma unroll
    for (int i = 0; i < 6; ++i) qdiag[i] = quadDamp[i*6 + i];
#pragma unroll
    for (int i = 0; i < 3; ++i) { cgcb[i] = cog[i]; cgcb[3+i] = cob[i]; }
    const float fgz = -mass[0] * 9.81f;
    const float fbz =  volume[0] * 1028.0f * 9.81f;

    // inv(mTot): fully-unrolled static-index fp32 Gauss-Jordan, no pivot
    // (mTot diagonally dominant; validated vs reference R2/R3). Registers
    // only; ~260 effective VALU ops after constant-folding of the identity.
    float Mi[36];
    {
        float a[36];
#pragma unroll
        for (int i = 0; i < 36; ++i) a[i] = mTot[i];
#pragma unroll
        for (int i = 0; i < 36; ++i) Mi[i] = 0.f;
#pragma unroll
        for (int i = 0; i < 6; ++i) Mi[i*6 + i] = 1.f;
#pragma unroll
        for (int col = 0; col < 6; ++col) {
            const float d = 1.0f / a[col*6 + col];
#pragma unroll
            for (int j = 0; j < 6; ++j) { a[col*6+j] *= d; Mi[col*6+j] *= d; }
#pragma unroll
            for (int r = 0; r < 6; ++r) {
                if (r == col) continue;
                const float f = a[r*6 + col];
#pragma unroll
                for (int j = 0; j < 6; ++j) {
                    a[r*6+j]  -= f * a[col*6+j];
                    Mi[r*6+j] -= f * Mi[col*6+j];
                }
            }
        }
    }

    __syncthreads();   // drains global_load_lds + cross-wave visibility

    // ---- two elements per thread, sequential (no extra live state) ----
#pragma unroll
    for (int e = 0; e < 2; ++e) {
        const int idx = e*256 + tid;           // row within block
        if (idx < nElem) {
            float U[6];
            {
                const float* gu = u + (size_t)(base + idx) * 6;
                const float2 a2 = *(const float2*)(gu);
                const float2 b2 = *(const float2*)(gu + 2);
                const float2 c2 = *(const float2*)(gu + 4);
                U[0]=a2.x; U[1]=a2.y; U[2]=b2.x; U[3]=b2.y; U[4]=c2.x; U[5]=c2.y;
            }
            float X[13];
#pragma unroll
            for (int j = 0; j < 13; ++j) X[j] = sx[idx*13 + j];

            float k1[13], X2[13], k2[13], Y[13];
            fossen_dot(X, U, Mi, mTot, linDamp, linDampFow, qdiag, cgcb,
                       fgz, fbz, k1);
#pragma unroll
            for (int j = 0; j < 13; ++j) X2[j] = X[j] + 0.1f * k1[j];
            fossen_dot(X2, U, Mi, mTot, linDamp, linDampFow, qdiag, cgcb,
                       fgz, fbz, k2);
#pragma unroll
            for (int j = 0; j < 13; ++j) Y[j] = X[j] + 0.05f * (k1[j] + k2[j]);

            const float nq  = Y[3]*Y[3] + Y[4]*Y[4] + Y[5]*Y[5] + Y[6]*Y[6];
            const float inv = 1.0f / sqrtf(nq);
            Y[3] *= inv; Y[4] *= inv; Y[5] *= inv; Y[6] *= inv;

            // own-row write-back (disjoint rows -> no barrier needed before)
#pragma unroll
            for (int j = 0; j < 13; ++j) sx[idx*13 + j] = Y[j];
        }
    }
    __syncthreads();

    if (nElem == ELEMS) {
        float4*       go = (float4*)(out + (size_t)base * 13);
        const float4* s4 = (const float4*)sx;
#pragma unroll
        for (int it = 0; it < 6; ++it) go[it*256 + tid] = s4[it*256 + tid];
        if (tid < 128) go[1536 + tid] = s4[1536 + tid];
    } else {
        for (int k = tid; k < nElem*13; k += 256) out[(size_t)base*13 + k] = sx[k];
    }
}

extern "C" void kernel_launch(void* const* d_in, const int* in_sizes, int n_in,
                              void* d_out, int out_size, void* d_ws, size_t ws_size,
                              hipStream_t stream)
{
    const float* x          = (const float*)d_in[0];
    const float* u          = (const float*)d_in[1];
    const float* mass       = (const float*)d_in[2];
    const float* volume     = (const float*)d_in[3];
    const float* cog        = (const float*)d_in[4];
    const float* cob        = (const float*)d_in[5];
    const float* mTot       = (const float*)d_in[6];
    const float* linDamp    = (const float*)d_in[7];
    const float* linDampFow = (const float*)d_in[8];
    const float* quadDamp   = (const float*)d_in[9];
    float*       out        = (float*)d_out;

    const int K = in_sizes[0] / 13;
    const int blocks = (K + ELEMS - 1) / ELEMS;
    auv_rk2_fused<<<blocks, 256, 0, stream>>>(x, u, mass, volume, cog, cob,
                                              mTot, linDamp, linDampFow,
                                              quadDamp, out, K);
}